// Round 1
// baseline (2444.896 us; speedup 1.0000x reference)
//
#include <hip/hip_runtime.h>
#include <stdint.h>

// ---------------------------------------------------------------------------
// StochasticKeyNet — R10: single persistent mega-kernel.
// Theory: 13 serialized small dispatches cost ~10us each in launch/ramp/drain
// while modeled compute is ~100-150us.  Fuse prep (weight pack + decode, made
// byte-disjoint so they run concurrently), all 9 MFMA convs, fc1, fc2+encode
// into ONE kernel with device-scope grid barriers.
// Residency proof (no-deadlock): __launch_bounds__(128,2) caps VGPR at 256 ->
// HW fits >=2 waves/SIMD = 4 blocks/CU; grid 768 <= 256 CU * 4 = 1024, LDS=0,
// so every block is co-resident before any barrier is reached.
// Barrier: two-level monotonic counters (8 leaf lines + root), agent-scope
// __hip_atomic (emits sc1 L2-writeback/invalidate for cross-XCD visibility),
// zeroed per replay by a hipMemsetAsync graph node.
// Conv math is IDENTICAL to R9 (same tiles, PF=2 pipeline, zero-page OOB).
// ---------------------------------------------------------------------------

#define B 128
#define ZPAD 2048   // leading zero page (elements) in each packed act buffer
#define NBLK 768
#define NTHR 128
#define JSTRIDE ((NBLK >> 3) * 2)   // 192 wave-units per XCD partition
#define LEAFN (NBLK >> 3)           // 96 blocks per leaf counter

typedef _Float16 f16_t;
typedef __attribute__((ext_vector_type(8))) _Float16 f16x8;
typedef __attribute__((ext_vector_type(4))) _Float16 f16x4;
typedef __attribute__((ext_vector_type(4))) float f32x4;

struct WArgs {
    const float* w[9]; const float* b[9];
    int Ci[9], Co[9], KS[9], Cp[9], NCG[9];
    int woff[10]; int boff[10];
};

// ---------------- grid barrier (monotonic, two-level) -----------------------
__device__ __forceinline__ void gbar(int* bar, int ph) {
    __syncthreads();                              // drains block's vmcnt too
    if (threadIdx.x == 0) {
        int* leaf = bar + (blockIdx.x & 7) * 16;  // 64B-padded leaf lines
        int* root = bar + 128;
        __threadfence();                          // agent release (wbl2 sc1)
        int old = __hip_atomic_fetch_add(leaf, 1, __ATOMIC_ACQ_REL,
                                         __HIP_MEMORY_SCOPE_AGENT);
        if (old == ph * LEAFN + (LEAFN - 1))
            __hip_atomic_fetch_add(root, 1, __ATOMIC_ACQ_REL,
                                   __HIP_MEMORY_SCOPE_AGENT);
        while (__hip_atomic_load(root, __ATOMIC_ACQUIRE,
                                 __HIP_MEMORY_SCOPE_AGENT) < (ph + 1) * 8)
            __builtin_amdgcn_s_sleep(4);
        __threadfence();                          // agent acquire (inv sc1)
    }
    __syncthreads();
}

// ---------------- phase 0: weight pack + zero-init + decode+pack ------------
// Zero-writer touches only ci%8 slots 3..7 (bytes 6..15 of each 16B group);
// decode writes slots 0..2 (bytes 0..5) -> byte-disjoint, no ordering needed.
__device__ void prep_phase(const WArgs& A,
                           const float* __restrict__ x0, const int* __restrict__ perm0,
                           const float* __restrict__ diag0,
                           f16_t* __restrict__ wp, float* __restrict__ bp,
                           f16_t* __restrict__ x8a, f16_t* __restrict__ x8b,
                           float* __restrict__ t0) {
    const int NT = NBLK * NTHR;
    const int gtid = blockIdx.x * NTHR + threadIdx.x;
    // zero pages of both act buffers (conv stores never write below ZPAD)
    for (int idx = gtid; idx < ZPAD; idx += NT) {
        x8a[idx] = (f16_t)0.f; x8b[idx] = (f16_t)0.f;
    }
    // zero ci%8 in 3..7 of the l0 input region of x8a (1024 px * 128 n)
    for (int idx = gtid; idx < 1024 * 128; idx += NT) {
        int p = idx >> 7, n = idx & 127;
        f16_t* base = x8a + ZPAD + p * 1024 + n * 8;
        base[3] = (f16_t)0.f;
        *(uint64_t*)(base + 4) = 0ull;            // 8-byte aligned (offset 8 of 16B group)
    }
    // bias pack
    for (int idx = gtid; idx < A.boff[9]; idx += NT) {
        int l = 0;
        while (idx >= A.boff[l + 1]) ++l;
        int co = idx - A.boff[l];
        bp[idx] = (co < A.Co[l]) ? A.b[l][co] : 0.f;
    }
    // weight pack to f16 [chunk][4][Cp][8]
    for (int idx = gtid; idx < A.woff[9]; idx += NT) {
        int l = 0;
        while (idx >= A.woff[l + 1]) ++l;
        int e = idx - A.woff[l];
        int j = e & 7;
        int t1_ = e >> 3;
        int Cp = A.Cp[l];
        int co = t1_ % Cp;
        int gg = t1_ / Cp;
        int ncg = A.NCG[l];
        int tap = gg / ncg, cg = gg - tap * ncg;
        int ks = A.KS[l];
        int kh = tap / ks, kw = tap - kh * ks;
        int ci = cg * 8 + j;
        float val = 0.f;
        if (co < A.Co[l] && tap < ks * ks && ci < A.Ci[l])
            val = A.w[l][(((size_t)co * A.Ci[l] + ci) * ks + kh) * ks + kw];
        wp[idx] = (f16_t)val;
    }
    // fused decode + f16 pack: v[perm[j]] = x[j]/diag[j]
    for (int idx = gtid; idx < 3073 * B; idx += NT) {
        int row = idx >> 7, n = idx & 127;
        int i = perm0[row];
        float val = x0[(size_t)row * B + n] / diag0[row];
        if (i < 3072) {
            int c = i >> 10, pp = i & 1023;
            x8a[ZPAD + pp * 1024 + n * 8 + c] = (f16_t)val;
        } else {
            t0[n] = val;
        }
    }
}

// ---------------- one conv layer (wave-granular persistent units) -----------
// Unit j decomposes exactly like R9's grid: nh (batch split) -> cog (co group)
// -> pixel, with XCD partition X = blockIdx&7 preserved for L2 locality.
// Block's two waves get consecutive j -> same pixel, adjacent cog (A/B dedup).
template <int KS, int NS, int NSPLIT, int CB, bool F32OUT,
          int Hi, int Wo_log2, int HWo, int STRD, int PAD,
          int NCG, int NCHUNK, int KGR, int Co, int Cp>
__device__ __forceinline__ void conv_layer(
    const f16_t* __restrict__ xin, const float* __restrict__ t_in,
    const f16_t* __restrict__ wp, const float* __restrict__ bp,
    f16_t* __restrict__ xout, float* __restrict__ t_out, float* __restrict__ f32out)
{
    constexpr int PF = 2;
    constexpr int MS = 4;
    constexpr int Wi = Hi;
    constexpr int PB8 = HWo / 8;
    constexpr int UJ = NSPLIT * CB * PB8;
    constexpr int HiWi = Hi * Wi;
    constexpr int HiWi4 = 4 * HiWi;
    constexpr int NCGHW = NCG * HiWi;
    const int wv = threadIdx.x >> 6;
    const int lane = threadIdx.x & 63;
    const int q = lane >> 4;       // quad -> k-group within chunk, C rows q*4..q*4+3
    const int r = lane & 15;       // A: co row / B,C: column n (mod 16)
    const int X = blockIdx.x & 7;

    // t-row relu (once per layer, block 0)
    if (blockIdx.x == 0 && threadIdx.x < B) {
        float tvv = fmaxf(t_in[threadIdx.x], 0.f);
        if (F32OUT) f32out[(size_t)Co * HWo * B + threadIdx.x] = tvv;
        else        t_out[threadIdx.x] = tvv;
    }

    for (int j = (blockIdx.x >> 3) * 2 + wv; j < UJ; j += JSTRIDE) {
        int nh = 0, j2 = j;
        if (NSPLIT > 1) { nh = j % NSPLIT; j2 = j / NSPLIT; }
        const int cog = (CB > 1) ? (j2 % CB) : 0;
        const int jp  = (CB > 1) ? (j2 / CB) : j2;
        const int p = X * PB8 + jp;
        const int co0 = cog * 64;
        const int ncol0 = nh * (NS * 16);
        const int ncol8 = ncol0 * 8;
        const int ho = p >> Wo_log2;
        const int wo = p & ((1 << Wo_log2) - 1);
        const f16_t* xdata = xin + ZPAD;

        float tv[NS];
#pragma unroll
        for (int ns = 0; ns < NS; ++ns) tv[ns] = t_in[ncol0 + ns * 16 + r];

        f32x4 acc[MS][NS];
#pragma unroll
        for (int ms = 0; ms < MS; ++ms) {
            float4 b4 = *(const float4*)(bp + co0 + ms * 16 + q * 4);
#pragma unroll
            for (int ns = 0; ns < NS; ++ns) {
                acc[ms][ns][0] = b4.x * tv[ns];
                acc[ms][ns][1] = b4.y * tv[ns];
                acc[ms][ns][2] = b4.z * tv[ns];
                acc[ms][ns][3] = b4.w * tv[ns];
            }
        }

        const int hb = ho * STRD - PAD, wb = wo * STRD - PAD;
        const int wend = wb + KS;

        int g = q, cg = q, hi = hb, wi = wb, cgHW;
        {
            while (cg >= NCG) { cg -= NCG; ++wi; if (wi == wend) { wi = wb; ++hi; } }
            cgHW = cg * HiWi;
        }

        f16x8 bf[PF][NS], af[PF][MS];

        auto advance = [&]() {
            g += 4; cg += 4; cgHW += HiWi4;
            if constexpr (NCG >= 4) {            // at most one wrap
                int c2 = cg - NCG;
                bool wrap = c2 >= 0;
                int wn = wi + 1;
                bool ww = wrap & (wn == wend);
                cg   = wrap ? c2 : cg;
                cgHW = wrap ? cgHW - NCGHW : cgHW;
                wi   = wrap ? (ww ? wb : wn) : wi;
                hi   = ww ? hi + 1 : hi;
            } else {
                while (cg >= NCG) { cg -= NCG; cgHW -= NCGHW; ++wi; if (wi == wend) { wi = wb; ++hi; } }
            }
        };
        auto loadB = [&](f16x8* bb8) {
            bool v = (g < KGR) & ((unsigned)hi < (unsigned)Hi) & ((unsigned)wi < (unsigned)Wi);
            int boff = (cgHW + hi * Wi + wi) << 10;        // *128*8 elements
            const f16_t* bb = xdata + (v ? boff : -ZPAD) + ncol8 + r * 8;
#pragma unroll
            for (int ns = 0; ns < NS; ++ns) bb8[ns] = *(const f16x8*)(bb + ns * 128);
        };
        auto loadA = [&](f16x8* a, int c) {
            int ac = c < NCHUNK ? c : NCHUNK - 1;          // clamp phantom chunks
            const f16_t* ap = wp + (((ac * 4 + q) * Cp) + co0 + r) * 8;
#pragma unroll
            for (int ms = 0; ms < MS; ++ms) a[ms] = *(const f16x8*)(ap + ms * 128);
        };
        auto domfma = [&](f16x8* a, f16x8* bb8) {
#pragma unroll
            for (int ms = 0; ms < MS; ++ms)
#pragma unroll
                for (int ns = 0; ns < NS; ++ns)
                    acc[ms][ns] = __builtin_amdgcn_mfma_f32_16x16x32_f16(a[ms], bb8[ns], acc[ms][ns], 0, 0, 0);
        };

        // phantom chunks (c >= NCHUNK) have g >= KGR -> B reads zero page -> no-op
#pragma unroll
        for (int pf = 0; pf < PF; ++pf) { loadB(bf[pf]); loadA(af[pf], pf); advance(); }
        constexpr int nck = ((NCHUNK + PF - 1) / PF) * PF;
        for (int c = 0; c < nck; c += PF) {
#pragma unroll
            for (int pf = 0; pf < PF; ++pf) {
                domfma(af[pf], bf[pf]);
                loadB(bf[pf]); loadA(af[pf], c + PF + pf); advance();
            }
        }

        if constexpr (!F32OUT) {
#pragma unroll
            for (int ms = 0; ms < MS; ++ms) {
                int cob = co0 + ms * 16 + q * 4;            // 4 consecutive co rows
                if (cob < Co) {
                    int off0 = ((cob >> 3) * HWo + p) * 1024 + (cob & 7) + ncol8 + r * 8;
#pragma unroll
                    for (int ns = 0; ns < NS; ++ns) {
                        f16x4 h;
                        h[0] = (f16_t)fmaxf(acc[ms][ns][0], 0.f);
                        h[1] = (f16_t)fmaxf(acc[ms][ns][1], 0.f);
                        h[2] = (f16_t)fmaxf(acc[ms][ns][2], 0.f);
                        h[3] = (f16_t)fmaxf(acc[ms][ns][3], 0.f);
                        *(f16x4*)(xout + ZPAD + off0 + ns * 128) = h;
                    }
                }
            }
        } else {
#pragma unroll
            for (int ms = 0; ms < MS; ++ms)
#pragma unroll
                for (int ns = 0; ns < NS; ++ns)
#pragma unroll
                    for (int e = 0; e < 4; ++e) {
                        int co = co0 + ms * 16 + q * 4 + e;
                        if (co < Co)
                            f32out[((size_t)co * HWo + p) * B + ncol0 + ns * 16 + r] =
                                fmaxf(acc[ms][ns][e], 0.f);
                    }
        }
    }
}

// ---------------- FC phases (block-granular, 128 threads = batch) -----------
__device__ __forceinline__ void fc_phase(const float* __restrict__ v, const float* __restrict__ w,
                                         const float* __restrict__ b, float* __restrict__ y,
                                         int K, int R, bool do_relu) {
    int r = blockIdx.x;
    int n = threadIdx.x;
    float t = v[(size_t)K * B + n];
    float val;
    if (r == R) {
        val = t;
    } else {
        float a0 = 0.f, a1 = 0.f, a2 = 0.f, a3 = 0.f;
        float a4 = 0.f, a5 = 0.f, a6 = 0.f, a7 = 0.f;
        const float* wr = w + (size_t)r * K;
        int k = 0;
        for (; k + 8 <= K; k += 8) {
            float4 w0 = *(const float4*)(wr + k);
            float4 w1 = *(const float4*)(wr + k + 4);
            float x0 = v[(size_t)(k + 0) * B + n];
            float x1 = v[(size_t)(k + 1) * B + n];
            float x2 = v[(size_t)(k + 2) * B + n];
            float x3 = v[(size_t)(k + 3) * B + n];
            float x4 = v[(size_t)(k + 4) * B + n];
            float x5 = v[(size_t)(k + 5) * B + n];
            float x6 = v[(size_t)(k + 6) * B + n];
            float x7 = v[(size_t)(k + 7) * B + n];
            a0 = fmaf(w0.x, x0, a0);
            a1 = fmaf(w0.y, x1, a1);
            a2 = fmaf(w0.z, x2, a2);
            a3 = fmaf(w0.w, x3, a3);
            a4 = fmaf(w1.x, x4, a4);
            a5 = fmaf(w1.y, x5, a5);
            a6 = fmaf(w1.z, x6, a6);
            a7 = fmaf(w1.w, x7, a7);
        }
        for (; k < K; ++k)
            a0 = fmaf(wr[k], v[(size_t)k * B + n], a0);
        val = b[r] * t + ((a0 + a1) + (a2 + a3)) + ((a4 + a5) + (a6 + a7));
    }
    if (do_relu) val = fmaxf(val, 0.f);
    y[(size_t)r * B + n] = val;
}

__device__ __forceinline__ void fc2_phase(const float* __restrict__ v, const float* __restrict__ w,
                                          const float* __restrict__ b, const int* __restrict__ perm,
                                          const float* __restrict__ diag, float* __restrict__ out) {
    int jrow = blockIdx.x;          // 0..10
    int n = threadIdx.x;            // 0..127
    int r = perm[jrow];
    float d = diag[jrow];
    float t = v[100 * B + n];
    float val;
    if (r == 10) {
        val = t;
    } else {
        float a0 = 0.f, a1 = 0.f, a2 = 0.f, a3 = 0.f;
        const float* wr = w + (size_t)r * 100;
        for (int k = 0; k < 100; k += 4) {
            float4 w4 = *(const float4*)(wr + k);
            a0 = fmaf(w4.x, v[(size_t)(k + 0) * B + n], a0);
            a1 = fmaf(w4.y, v[(size_t)(k + 1) * B + n], a1);
            a2 = fmaf(w4.z, v[(size_t)(k + 2) * B + n], a2);
            a3 = fmaf(w4.w, v[(size_t)(k + 3) * B + n], a3);
        }
        val = b[r] * t + (a0 + a1) + (a2 + a3);
    }
    out[(size_t)jrow * B + n] = d * val;
}

// ---------------- the mega-kernel -------------------------------------------
__global__ __launch_bounds__(NTHR, 2) void meganet_kernel(
    WArgs A,
    const float* __restrict__ x0, const int* __restrict__ perm0, const float* __restrict__ diag0,
    const int* __restrict__ perm11, const float* __restrict__ diag11,
    const float* __restrict__ fw1, const float* __restrict__ fb1,
    const float* __restrict__ fw2, const float* __restrict__ fb2,
    f16_t* wp, float* bp, f16_t* x8a, f16_t* x8b,
    float* t0, float* t1, float* bufA, float* bufB, float* out, int* bar)
{
    prep_phase(A, x0, perm0, diag0, wp, bp, x8a, x8b, t0);
    gbar(bar, 0);
    //            KS NS SP CB F32   Hi WoL HWo  ST PD  NCG NCHK KGR  Co  Cp
    conv_layer<3, 8, 1, 2, false, 32, 5, 1024, 1, 1,  1,  3,   9,  96, 128>(
        x8a, t0, wp + A.woff[0], bp + A.boff[0], x8b, t1, nullptr);
    gbar(bar, 1);
    conv_layer<3, 8, 1, 2, false, 32, 5, 1024, 1, 1, 12, 27, 108,  96, 128>(
        x8b, t1, wp + A.woff[1], bp + A.boff[1], x8a, t0, nullptr);
    gbar(bar, 2);
    conv_layer<3, 4, 2, 2, false, 32, 4,  256, 2, 1, 12, 27, 108,  96, 128>(
        x8a, t0, wp + A.woff[2], bp + A.boff[2], x8b, t1, nullptr);
    gbar(bar, 3);
    conv_layer<3, 8, 1, 3, false, 16, 4,  256, 1, 1, 12, 27, 108, 192, 192>(
        x8b, t1, wp + A.woff[3], bp + A.boff[3], x8a, t0, nullptr);
    gbar(bar, 4);
    conv_layer<3, 8, 1, 3, false, 16, 4,  256, 1, 1, 24, 54, 216, 192, 192>(
        x8a, t0, wp + A.woff[4], bp + A.boff[4], x8b, t1, nullptr);
    gbar(bar, 5);
    conv_layer<3, 2, 4, 3, false, 16, 3,   64, 2, 1, 24, 54, 216, 192, 192>(
        x8b, t1, wp + A.woff[5], bp + A.boff[5], x8a, t0, nullptr);
    gbar(bar, 6);
    conv_layer<3, 2, 4, 3, false,  8, 3,   64, 1, 1, 24, 54, 216, 192, 192>(
        x8a, t0, wp + A.woff[6], bp + A.boff[6], x8b, t1, nullptr);
    gbar(bar, 7);
    conv_layer<1, 2, 4, 3, false,  8, 3,   64, 1, 0, 24,  6,  24, 192, 192>(
        x8b, t1, wp + A.woff[7], bp + A.boff[7], x8a, t0, nullptr);
    gbar(bar, 8);
    conv_layer<1, 2, 4, 1, true,   8, 3,   64, 1, 0, 24,  6,  24,  10,  64>(
        x8a, t0, wp + A.woff[8], bp + A.boff[8], nullptr, nullptr, bufA);
    gbar(bar, 9);
    if (blockIdx.x <= 100) fc_phase(bufA, fw1, fb1, bufB, 640, 100, true);
    gbar(bar, 10);
    if (blockIdx.x < 11) fc2_phase(bufB, fw2, fb2, perm11, diag11, out);
}

// ---------------------------------------------------------------------------

extern "C" void kernel_launch(void* const* d_in, const int* in_sizes, int n_in,
                              void* d_out, int out_size, void* d_ws, size_t ws_size,
                              hipStream_t stream) {
    const float* x0 = (const float*)d_in[0];
    const int*   perm[12];
    const float* diag[12];
    for (int i = 0; i < 12; ++i) {
        perm[i] = (const int*)d_in[1 + 2 * i];
        diag[i] = (const float*)d_in[2 + 2 * i];
    }
    const float* wts[9];
    const float* bia[9];
    for (int j = 0; j < 9; ++j) {
        wts[j] = (const float*)d_in[25 + 2 * j];
        bia[j] = (const float*)d_in[26 + 2 * j];
    }
    const float* fw1 = (const float*)d_in[43];
    const float* fb1 = (const float*)d_in[44];
    const float* fw2 = (const float*)d_in[45];
    const float* fb2 = (const float*)d_in[46];
    float* out = (float*)d_out;

    // ----- layer tables (for weight pack offsets) -----
    static const int CiA[9]  = {3, 96, 96, 96, 192, 192, 192, 192, 192};
    static const int CoA[9]  = {96, 96, 96, 192, 192, 192, 192, 192, 10};
    static const int KSA[9]  = {3, 3, 3, 3, 3, 3, 3, 1, 1};
    static const int CpA[9]  = {128, 128, 128, 192, 192, 192, 192, 192, 64};
    static const int NCGA[9] = {1, 12, 12, 12, 24, 24, 24, 24, 24};
    static const int NCHK[9] = {3, 27, 27, 27, 54, 54, 54, 6, 6};

    // ----- workspace layout (same as R9, + barrier counters) -----
    char* wsb = (char*)d_ws;
    const size_t BUF_F32  = 1574912;
    const size_t X8_BYTES = (size_t)(ZPAD + 12 * 1024 * 1024) * 2;
    float* bufA = (float*)wsb;
    float* bufB = (float*)(wsb + BUF_F32);
    f16_t* x8a  = (f16_t*)(wsb + 2 * BUF_F32);
    f16_t* x8b  = (f16_t*)(wsb + 2 * BUF_F32 + X8_BYTES);
    f16_t* wpb  = (f16_t*)(wsb + 2 * BUF_F32 + 2 * X8_BYTES);
    const size_t WP_BYTES = 2888704;
    float* bpb  = (float*)(wsb + 2 * BUF_F32 + 2 * X8_BYTES + WP_BYTES);
    float* t0   = (float*)((char*)bpb + 8192);
    float* t1   = t0 + 256;
    int*   bar  = (int*)((char*)bpb + 12288);   // 8 leaf lines + root, <4KB

    WArgs WA;
    int wo = 0, bo = 0;
    for (int l = 0; l < 9; ++l) {
        WA.w[l] = wts[l]; WA.b[l] = bia[l];
        WA.Ci[l] = CiA[l]; WA.Co[l] = CoA[l]; WA.KS[l] = KSA[l];
        WA.Cp[l] = CpA[l]; WA.NCG[l] = NCGA[l];
        WA.woff[l] = wo; wo += NCHK[l] * 4 * CpA[l] * 8;
        WA.boff[l] = bo; bo += CpA[l];
    }
    WA.woff[9] = wo; WA.boff[9] = bo;

    // barrier counters must start at 0 each replay (workspace is poisoned)
    hipMemsetAsync(bar, 0, 4096, stream);

    meganet_kernel<<<NBLK, NTHR, 0, stream>>>(
        WA, x0, perm[0], diag[0], perm[11], diag[11],
        fw1, fb1, fw2, fb2,
        wpb, bpb, x8a, x8b, t0, t1, bufA, bufB, out, bar);
}

// Round 2
// 373.090 us; speedup vs baseline: 6.5531x; 6.5531x over previous
//
#include <hip/hip_runtime.h>
#include <stdint.h>

// ---------------------------------------------------------------------------
// StochasticKeyNet — R11: mega-kernel with cache-op-minimal grid barrier.
// R10 post-mortem: 2368us, MfmaUtil 1.5% -> ~190us/barrier of serialized L2
// maintenance (per-poll ACQUIRE buffer_inv sc1 + per-block wbl2 storms).
// R11 barrier: census of physical XCD (s_getreg XCC_ID) at entry; per barrier
// only the LAST arriver of each XCD issues release (wbl2 sc1) + root bump;
// all polls are RELAXED (no cache ops); one acquire (inv sc1) per XCD; other
// blocks do a local L1-only invalidate (buffer_inv sc0).
// Residency: __launch_bounds__(128,2) -> VGPR<=256 -> >=4 blocks/CU -> 1024
// blocks co-resident on 256 CUs (LDS=0).  Conv math identical to R9/R10.
// ---------------------------------------------------------------------------

#define B 128
#define ZPAD 2048   // leading zero page (elements) in each packed act buffer
#define NBLK 1024
#define NTHR 128
#define JSTRIDE ((NBLK >> 3) * 2)   // 256 wave-units per work partition
#define AGT __HIP_MEMORY_SCOPE_AGENT

typedef _Float16 f16_t;
typedef __attribute__((ext_vector_type(8))) _Float16 f16x8;
typedef __attribute__((ext_vector_type(4))) _Float16 f16x4;
typedef __attribute__((ext_vector_type(4))) float f32x4;

struct WArgs {
    const float* w[9]; const float* b[9];
    int Ci[9], Co[9], KS[9], Cp[9], NCG[9];
    int woff[10]; int boff[10];
};

// ---------------- physical XCD id (learn_hip m09: returns 0..7) -------------
__device__ __forceinline__ int xcc_id() {
    int x;
    asm("s_getreg_b32 %0, hwreg(20, 0, 32)" : "=s"(x));   // HW_REG_XCC_ID
    return x & 7;
}

// ---------------- grid barrier --------------------------------------------
// bar layout (ints): leaf arrive x*32 (0..224) | leaf_done 256+x*32 |
// root 512 | census cnt 544..551.  All zeroed per launch by hipMemsetAsync.
__device__ __forceinline__ void gbar(int* bar, int ph) {
    __syncthreads();                               // drains vmcnt: stores in L2
    if (threadIdx.x == 0) {
        const int x = xcc_id();
        int* leaf  = bar + x * 32;
        int* ldone = bar + 256 + x * 32;
        int* root  = bar + 512;
        int* cnt   = bar + 544;
        if (ph == 0) {                             // census settle (entry regs)
            for (;;) {
                int s = 0;
#pragma unroll
                for (int k = 0; k < 8; ++k)
                    s += __hip_atomic_load(cnt + k, __ATOMIC_RELAXED, AGT);
                if (s == NBLK) break;
                __builtin_amdgcn_s_sleep(2);
            }
        }
        const int myc = __hip_atomic_load(cnt + x, __ATOMIC_RELAXED, AGT);
        int nact = 0;
#pragma unroll
        for (int k = 0; k < 8; ++k)
            nact += (__hip_atomic_load(cnt + k, __ATOMIC_RELAXED, AGT) != 0) ? 1 : 0;
        int old = __hip_atomic_fetch_add(leaf, 1, __ATOMIC_RELAXED, AGT);
        if (old == (ph + 1) * myc - 1) {
            // last arriver of this physical XCD: all local blocks' stores are
            // already in this L2 (their syncthreads drained vmcnt) -> one wbl2
            // publishes everything; then signal root.
            __builtin_amdgcn_fence(__ATOMIC_RELEASE, "agent");   // wbl2 sc1
            __hip_atomic_fetch_add(root, 1, __ATOMIC_RELAXED, AGT);
            while (__hip_atomic_load(root, __ATOMIC_RELAXED, AGT) < (ph + 1) * nact)
                __builtin_amdgcn_s_sleep(8);
            __builtin_amdgcn_fence(__ATOMIC_ACQUIRE, "agent");   // inv L1+L2
            __hip_atomic_store(ldone, ph + 1, __ATOMIC_RELAXED, AGT);
        } else {
            while (__hip_atomic_load(ldone, __ATOMIC_RELAXED, AGT) < ph + 1)
                __builtin_amdgcn_s_sleep(8);
            // XCD L2 already invalidated by designated block; local L1 only.
            asm volatile("buffer_inv sc0\n\ts_waitcnt vmcnt(0)" ::: "memory");
        }
    }
    __syncthreads();
}

// ---------------- phase 0: weight pack + zero-init + decode+pack ------------
__device__ void prep_phase(const WArgs& A,
                           const float* __restrict__ x0, const int* __restrict__ perm0,
                           const float* __restrict__ diag0,
                           f16_t* __restrict__ wp, float* __restrict__ bp,
                           f16_t* __restrict__ x8a, f16_t* __restrict__ x8b,
                           float* __restrict__ t0) {
    const int NT = NBLK * NTHR;
    const int gtid = blockIdx.x * NTHR + threadIdx.x;
    // zero pages of both act buffers (conv stores never write below ZPAD)
    for (int idx = gtid; idx < ZPAD; idx += NT) {
        x8a[idx] = (f16_t)0.f; x8b[idx] = (f16_t)0.f;
    }
    // zero ci%8 slots 3..7 of the l0 input region of x8a (byte-disjoint from
    // decode's slots 0..2)
    for (int idx = gtid; idx < 1024 * 128; idx += NT) {
        int p = idx >> 7, n = idx & 127;
        f16_t* base = x8a + ZPAD + p * 1024 + n * 8;
        base[3] = (f16_t)0.f;
        *(uint64_t*)(base + 4) = 0ull;
    }
    // bias pack
    for (int idx = gtid; idx < A.boff[9]; idx += NT) {
        int l = 0;
        while (idx >= A.boff[l + 1]) ++l;
        int co = idx - A.boff[l];
        bp[idx] = (co < A.Co[l]) ? A.b[l][co] : 0.f;
    }
    // weight pack to f16 [chunk][4][Cp][8]
    for (int idx = gtid; idx < A.woff[9]; idx += NT) {
        int l = 0;
        while (idx >= A.woff[l + 1]) ++l;
        int e = idx - A.woff[l];
        int j = e & 7;
        int t1_ = e >> 3;
        int Cp = A.Cp[l];
        int co = t1_ % Cp;
        int gg = t1_ / Cp;
        int ncg = A.NCG[l];
        int tap = gg / ncg, cg = gg - tap * ncg;
        int ks = A.KS[l];
        int kh = tap / ks, kw = tap - kh * ks;
        int ci = cg * 8 + j;
        float val = 0.f;
        if (co < A.Co[l] && tap < ks * ks && ci < A.Ci[l])
            val = A.w[l][(((size_t)co * A.Ci[l] + ci) * ks + kh) * ks + kw];
        wp[idx] = (f16_t)val;
    }
    // fused decode + f16 pack: v[perm[j]] = x[j]/diag[j]
    for (int idx = gtid; idx < 3073 * B; idx += NT) {
        int row = idx >> 7, n = idx & 127;
        int i = perm0[row];
        float val = x0[(size_t)row * B + n] / diag0[row];
        if (i < 3072) {
            int c = i >> 10, pp = i & 1023;
            x8a[ZPAD + pp * 1024 + n * 8 + c] = (f16_t)val;
        } else {
            t0[n] = val;
        }
    }
}

// ---------------- one conv layer (wave-granular persistent units) -----------
template <int KS, int NS, int NSPLIT, int CB, bool F32OUT,
          int Hi, int Wo_log2, int HWo, int STRD, int PAD,
          int NCG, int NCHUNK, int KGR, int Co, int Cp>
__device__ __forceinline__ void conv_layer(
    const f16_t* __restrict__ xin, const float* __restrict__ t_in,
    const f16_t* __restrict__ wp, const float* __restrict__ bp,
    f16_t* __restrict__ xout, float* __restrict__ t_out, float* __restrict__ f32out)
{
    constexpr int PF = 2;
    constexpr int MS = 4;
    constexpr int Wi = Hi;
    constexpr int PB8 = HWo / 8;
    constexpr int UJ = NSPLIT * CB * PB8;
    constexpr int HiWi = Hi * Wi;
    constexpr int HiWi4 = 4 * HiWi;
    constexpr int NCGHW = NCG * HiWi;
    const int wv = threadIdx.x >> 6;
    const int lane = threadIdx.x & 63;
    const int q = lane >> 4;
    const int r = lane & 15;
    const int X = blockIdx.x & 7;

    // t-row relu (once per layer, block 0)
    if (blockIdx.x == 0 && threadIdx.x < B) {
        float tvv = fmaxf(t_in[threadIdx.x], 0.f);
        if (F32OUT) f32out[(size_t)Co * HWo * B + threadIdx.x] = tvv;
        else        t_out[threadIdx.x] = tvv;
    }

    for (int j = (blockIdx.x >> 3) * 2 + wv; j < UJ; j += JSTRIDE) {
        int nh = 0, j2 = j;
        if (NSPLIT > 1) { nh = j % NSPLIT; j2 = j / NSPLIT; }
        const int cog = (CB > 1) ? (j2 % CB) : 0;
        const int jp  = (CB > 1) ? (j2 / CB) : j2;
        const int p = X * PB8 + jp;
        const int co0 = cog * 64;
        const int ncol0 = nh * (NS * 16);
        const int ncol8 = ncol0 * 8;
        const int ho = p >> Wo_log2;
        const int wo = p & ((1 << Wo_log2) - 1);
        const f16_t* xdata = xin + ZPAD;

        float tv[NS];
#pragma unroll
        for (int ns = 0; ns < NS; ++ns) tv[ns] = t_in[ncol0 + ns * 16 + r];

        f32x4 acc[MS][NS];
#pragma unroll
        for (int ms = 0; ms < MS; ++ms) {
            float4 b4 = *(const float4*)(bp + co0 + ms * 16 + q * 4);
#pragma unroll
            for (int ns = 0; ns < NS; ++ns) {
                acc[ms][ns][0] = b4.x * tv[ns];
                acc[ms][ns][1] = b4.y * tv[ns];
                acc[ms][ns][2] = b4.z * tv[ns];
                acc[ms][ns][3] = b4.w * tv[ns];
            }
        }

        const int hb = ho * STRD - PAD, wb = wo * STRD - PAD;
        const int wend = wb + KS;

        int g = q, cg = q, hi = hb, wi = wb, cgHW;
        {
            while (cg >= NCG) { cg -= NCG; ++wi; if (wi == wend) { wi = wb; ++hi; } }
            cgHW = cg * HiWi;
        }

        f16x8 bf[PF][NS], af[PF][MS];

        auto advance = [&]() {
            g += 4; cg += 4; cgHW += HiWi4;
            if constexpr (NCG >= 4) {            // at most one wrap
                int c2 = cg - NCG;
                bool wrap = c2 >= 0;
                int wn = wi + 1;
                bool ww = wrap & (wn == wend);
                cg   = wrap ? c2 : cg;
                cgHW = wrap ? cgHW - NCGHW : cgHW;
                wi   = wrap ? (ww ? wb : wn) : wi;
                hi   = ww ? hi + 1 : hi;
            } else {
                while (cg >= NCG) { cg -= NCG; cgHW -= NCGHW; ++wi; if (wi == wend) { wi = wb; ++hi; } }
            }
        };
        auto loadB = [&](f16x8* bb8) {
            bool v = (g < KGR) & ((unsigned)hi < (unsigned)Hi) & ((unsigned)wi < (unsigned)Wi);
            int boff = (cgHW + hi * Wi + wi) << 10;        // *128*8 elements
            const f16_t* bb = xdata + (v ? boff : -ZPAD) + ncol8 + r * 8;
#pragma unroll
            for (int ns = 0; ns < NS; ++ns) bb8[ns] = *(const f16x8*)(bb + ns * 128);
        };
        auto loadA = [&](f16x8* a, int c) {
            int ac = c < NCHUNK ? c : NCHUNK - 1;          // clamp phantom chunks
            const f16_t* ap = wp + (((ac * 4 + q) * Cp) + co0 + r) * 8;
#pragma unroll
            for (int ms = 0; ms < MS; ++ms) a[ms] = *(const f16x8*)(ap + ms * 128);
        };
        auto domfma = [&](f16x8* a, f16x8* bb8) {
#pragma unroll
            for (int ms = 0; ms < MS; ++ms)
#pragma unroll
                for (int ns = 0; ns < NS; ++ns)
                    acc[ms][ns] = __builtin_amdgcn_mfma_f32_16x16x32_f16(a[ms], bb8[ns], acc[ms][ns], 0, 0, 0);
        };

#pragma unroll
        for (int pf = 0; pf < PF; ++pf) { loadB(bf[pf]); loadA(af[pf], pf); advance(); }
        constexpr int nck = ((NCHUNK + PF - 1) / PF) * PF;
        for (int c = 0; c < nck; c += PF) {
#pragma unroll
            for (int pf = 0; pf < PF; ++pf) {
                domfma(af[pf], bf[pf]);
                loadB(bf[pf]); loadA(af[pf], c + PF + pf); advance();
            }
        }

        if constexpr (!F32OUT) {
#pragma unroll
            for (int ms = 0; ms < MS; ++ms) {
                int cob = co0 + ms * 16 + q * 4;
                if (cob < Co) {
                    int off0 = ((cob >> 3) * HWo + p) * 1024 + (cob & 7) + ncol8 + r * 8;
#pragma unroll
                    for (int ns = 0; ns < NS; ++ns) {
                        f16x4 h;
                        h[0] = (f16_t)fmaxf(acc[ms][ns][0], 0.f);
                        h[1] = (f16_t)fmaxf(acc[ms][ns][1], 0.f);
                        h[2] = (f16_t)fmaxf(acc[ms][ns][2], 0.f);
                        h[3] = (f16_t)fmaxf(acc[ms][ns][3], 0.f);
                        *(f16x4*)(xout + ZPAD + off0 + ns * 128) = h;
                    }
                }
            }
        } else {
#pragma unroll
            for (int ms = 0; ms < MS; ++ms)
#pragma unroll
                for (int ns = 0; ns < NS; ++ns)
#pragma unroll
                    for (int e = 0; e < 4; ++e) {
                        int co = co0 + ms * 16 + q * 4 + e;
                        if (co < Co)
                            f32out[((size_t)co * HWo + p) * B + ncol0 + ns * 16 + r] =
                                fmaxf(acc[ms][ns][e], 0.f);
                    }
        }
    }
}

// ---------------- FC phases -------------------------------------------------
__device__ __forceinline__ void fc_phase(const float* __restrict__ v, const float* __restrict__ w,
                                         const float* __restrict__ b, float* __restrict__ y,
                                         int K, int R, bool do_relu) {
    int r = blockIdx.x;
    int n = threadIdx.x;
    float t = v[(size_t)K * B + n];
    float val;
    if (r == R) {
        val = t;
    } else {
        float a0 = 0.f, a1 = 0.f, a2 = 0.f, a3 = 0.f;
        float a4 = 0.f, a5 = 0.f, a6 = 0.f, a7 = 0.f;
        const float* wr = w + (size_t)r * K;
        int k = 0;
        for (; k + 8 <= K; k += 8) {
            float4 w0 = *(const float4*)(wr + k);
            float4 w1 = *(const float4*)(wr + k + 4);
            float x0 = v[(size_t)(k + 0) * B + n];
            float x1 = v[(size_t)(k + 1) * B + n];
            float x2 = v[(size_t)(k + 2) * B + n];
            float x3 = v[(size_t)(k + 3) * B + n];
            float x4 = v[(size_t)(k + 4) * B + n];
            float x5 = v[(size_t)(k + 5) * B + n];
            float x6 = v[(size_t)(k + 6) * B + n];
            float x7 = v[(size_t)(k + 7) * B + n];
            a0 = fmaf(w0.x, x0, a0);
            a1 = fmaf(w0.y, x1, a1);
            a2 = fmaf(w0.z, x2, a2);
            a3 = fmaf(w0.w, x3, a3);
            a4 = fmaf(w1.x, x4, a4);
            a5 = fmaf(w1.y, x5, a5);
            a6 = fmaf(w1.z, x6, a6);
            a7 = fmaf(w1.w, x7, a7);
        }
        for (; k < K; ++k)
            a0 = fmaf(wr[k], v[(size_t)k * B + n], a0);
        val = b[r] * t + ((a0 + a1) + (a2 + a3)) + ((a4 + a5) + (a6 + a7));
    }
    if (do_relu) val = fmaxf(val, 0.f);
    y[(size_t)r * B + n] = val;
}

__device__ __forceinline__ void fc2_phase(const float* __restrict__ v, const float* __restrict__ w,
                                          const float* __restrict__ b, const int* __restrict__ perm,
                                          const float* __restrict__ diag, float* __restrict__ out) {
    int jrow = blockIdx.x;
    int n = threadIdx.x;
    int r = perm[jrow];
    float d = diag[jrow];
    float t = v[100 * B + n];
    float val;
    if (r == 10) {
        val = t;
    } else {
        float a0 = 0.f, a1 = 0.f, a2 = 0.f, a3 = 0.f;
        const float* wr = w + (size_t)r * 100;
        for (int k = 0; k < 100; k += 4) {
            float4 w4 = *(const float4*)(wr + k);
            a0 = fmaf(w4.x, v[(size_t)(k + 0) * B + n], a0);
            a1 = fmaf(w4.y, v[(size_t)(k + 1) * B + n], a1);
            a2 = fmaf(w4.z, v[(size_t)(k + 2) * B + n], a2);
            a3 = fmaf(w4.w, v[(size_t)(k + 3) * B + n], a3);
        }
        val = b[r] * t + (a0 + a1) + (a2 + a3);
    }
    out[(size_t)jrow * B + n] = d * val;
}

// ---------------- the mega-kernel -------------------------------------------
__global__ __launch_bounds__(NTHR, 2) void meganet_kernel(
    WArgs A,
    const float* __restrict__ x0, const int* __restrict__ perm0, const float* __restrict__ diag0,
    const int* __restrict__ perm11, const float* __restrict__ diag11,
    const float* __restrict__ fw1, const float* __restrict__ fb1,
    const float* __restrict__ fw2, const float* __restrict__ fb2,
    f16_t* wp, float* bp, f16_t* x8a, f16_t* x8b,
    float* t0, float* t1, float* bufA, float* bufB, float* out, int* bar)
{
    // census: register this block's physical XCD (stable for kernel lifetime)
    if (threadIdx.x == 0)
        __hip_atomic_fetch_add(bar + 544 + xcc_id(), 1, __ATOMIC_RELAXED, AGT);

    prep_phase(A, x0, perm0, diag0, wp, bp, x8a, x8b, t0);
    gbar(bar, 0);
    //            KS NS SP CB F32   Hi WoL HWo  ST PD  NCG NCHK KGR  Co  Cp
    conv_layer<3, 8, 1, 2, false, 32, 5, 1024, 1, 1,  1,  3,   9,  96, 128>(
        x8a, t0, wp + A.woff[0], bp + A.boff[0], x8b, t1, nullptr);
    gbar(bar, 1);
    conv_layer<3, 8, 1, 2, false, 32, 5, 1024, 1, 1, 12, 27, 108,  96, 128>(
        x8b, t1, wp + A.woff[1], bp + A.boff[1], x8a, t0, nullptr);
    gbar(bar, 2);
    conv_layer<3, 2, 4, 2, false, 32, 4,  256, 2, 1, 12, 27, 108,  96, 128>(
        x8a, t0, wp + A.woff[2], bp + A.boff[2], x8b, t1, nullptr);
    gbar(bar, 3);
    conv_layer<3, 4, 2, 3, false, 16, 4,  256, 1, 1, 12, 27, 108, 192, 192>(
        x8b, t1, wp + A.woff[3], bp + A.boff[3], x8a, t0, nullptr);
    gbar(bar, 4);
    conv_layer<3, 4, 2, 3, false, 16, 4,  256, 1, 1, 24, 54, 216, 192, 192>(
        x8a, t0, wp + A.woff[4], bp + A.boff[4], x8b, t1, nullptr);
    gbar(bar, 5);
    conv_layer<3, 2, 4, 3, false, 16, 3,   64, 2, 1, 24, 54, 216, 192, 192>(
        x8b, t1, wp + A.woff[5], bp + A.boff[5], x8a, t0, nullptr);
    gbar(bar, 6);
    conv_layer<3, 2, 4, 3, false,  8, 3,   64, 1, 1, 24, 54, 216, 192, 192>(
        x8a, t0, wp + A.woff[6], bp + A.boff[6], x8b, t1, nullptr);
    gbar(bar, 7);
    conv_layer<1, 2, 4, 3, false,  8, 3,   64, 1, 0, 24,  6,  24, 192, 192>(
        x8b, t1, wp + A.woff[7], bp + A.boff[7], x8a, t0, nullptr);
    gbar(bar, 8);
    conv_layer<1, 2, 4, 1, true,   8, 3,   64, 1, 0, 24,  6,  24,  10,  64>(
        x8a, t0, wp + A.woff[8], bp + A.boff[8], nullptr, nullptr, bufA);
    gbar(bar, 9);
    if (blockIdx.x <= 100) fc_phase(bufA, fw1, fb1, bufB, 640, 100, true);
    gbar(bar, 10);
    if (blockIdx.x < 11) fc2_phase(bufB, fw2, fb2, perm11, diag11, out);
}

// ---------------------------------------------------------------------------

extern "C" void kernel_launch(void* const* d_in, const int* in_sizes, int n_in,
                              void* d_out, int out_size, void* d_ws, size_t ws_size,
                              hipStream_t stream) {
    const float* x0 = (const float*)d_in[0];
    const int*   perm[12];
    const float* diag[12];
    for (int i = 0; i < 12; ++i) {
        perm[i] = (const int*)d_in[1 + 2 * i];
        diag[i] = (const float*)d_in[2 + 2 * i];
    }
    const float* wts[9];
    const float* bia[9];
    for (int j = 0; j < 9; ++j) {
        wts[j] = (const float*)d_in[25 + 2 * j];
        bia[j] = (const float*)d_in[26 + 2 * j];
    }
    const float* fw1 = (const float*)d_in[43];
    const float* fb1 = (const float*)d_in[44];
    const float* fw2 = (const float*)d_in[45];
    const float* fb2 = (const float*)d_in[46];
    float* out = (float*)d_out;

    static const int CiA[9]  = {3, 96, 96, 96, 192, 192, 192, 192, 192};
    static const int CoA[9]  = {96, 96, 96, 192, 192, 192, 192, 192, 10};
    static const int KSA[9]  = {3, 3, 3, 3, 3, 3, 3, 1, 1};
    static const int CpA[9]  = {128, 128, 128, 192, 192, 192, 192, 192, 64};
    static const int NCGA[9] = {1, 12, 12, 12, 24, 24, 24, 24, 24};
    static const int NCHK[9] = {3, 27, 27, 27, 54, 54, 54, 6, 6};

    // ----- workspace layout (same as R9/R10, + barrier block) -----
    char* wsb = (char*)d_ws;
    const size_t BUF_F32  = 1574912;
    const size_t X8_BYTES = (size_t)(ZPAD + 12 * 1024 * 1024) * 2;
    float* bufA = (float*)wsb;
    float* bufB = (float*)(wsb + BUF_F32);
    f16_t* x8a  = (f16_t*)(wsb + 2 * BUF_F32);
    f16_t* x8b  = (f16_t*)(wsb + 2 * BUF_F32 + X8_BYTES);
    f16_t* wpb  = (f16_t*)(wsb + 2 * BUF_F32 + 2 * X8_BYTES);
    const size_t WP_BYTES = 2888704;
    float* bpb  = (float*)(wsb + 2 * BUF_F32 + 2 * X8_BYTES + WP_BYTES);
    float* t0   = (float*)((char*)bpb + 8192);
    float* t1   = t0 + 256;
    int*   bar  = (int*)((char*)bpb + 12288);   // arrive/done/root/census < 4KB

    WArgs WA;
    int wo = 0, bo = 0;
    for (int l = 0; l < 9; ++l) {
        WA.w[l] = wts[l]; WA.b[l] = bia[l];
        WA.Ci[l] = CiA[l]; WA.Co[l] = CoA[l]; WA.KS[l] = KSA[l];
        WA.Cp[l] = CpA[l]; WA.NCG[l] = NCGA[l];
        WA.woff[l] = wo; wo += NCHK[l] * 4 * CpA[l] * 8;
        WA.boff[l] = bo; bo += CpA[l];
    }
    WA.woff[9] = wo; WA.boff[9] = bo;

    // barrier/census counters must start at 0 each replay
    hipMemsetAsync(bar, 0, 4096, stream);

    meganet_kernel<<<NBLK, NTHR, 0, stream>>>(
        WA, x0, perm[0], diag[0], perm[11], diag[11],
        fw1, fb1, fw2, fb2,
        wpb, bpb, x8a, x8b, t0, t1, bufA, bufB, out, bar);
}